// Round 3
// baseline (985.783 us; speedup 1.0000x reference)
//
#include <hip/hip_runtime.h>

namespace {

constexpr int kB = 64;
constexpr int kP = 25000;
constexpr int kT = 16;
constexpr int kC = 81;
constexpr int kRowsPerBlk = 64;            // ce kernel rows per block
constexpr int kChunks = 16;                // prior chunks for match kernel
constexpr int kChunkP = (kP + kChunks - 1) / kChunks;  // 1563
constexpr float kThresh = 0.5f;

__device__ __forceinline__ float smooth_l1(float d) {
  float ad = fabsf(d);
  return ad < 1.0f ? 0.5f * d * d : ad - 0.5f;
}

// ---------------------------------------------------------------------------
// Kernel A: per-prior best truth -> mcode; per-(b,t,chunk) best prior written
// UNCONDITIONALLY to its own slot (no atomics -> no pre-zero -> no memset
// dispatch). Block (0,0) also zeroes num_pos/acc/counter (consumed only by
// later kernels; kernel boundary orders the writes).
// packed u64 = (iou_bits << 32) | (0xFFFFFFFF - p): max => max iou, ties
// prefer smaller p (first occurrence, matches jnp.argmax).
// ---------------------------------------------------------------------------
__global__ __launch_bounds__(256) void match1_kernel(
    const float* __restrict__ priors,     // [P,4] (cx,cy,w,h)
    const float* __restrict__ targets,    // [B,T,5]
    unsigned char* __restrict__ mcode,    // [B,P] out
    unsigned long long* __restrict__ best_pc,  // [B,T,kChunks] out
    int* __restrict__ num_pos,            // [B] zeroed here
    float* __restrict__ acc,              // [3] zeroed here
    int* __restrict__ counter) {          // [1] zeroed here
  const int chunk = blockIdx.x;
  const int b = blockIdx.y;
  const int tid = threadIdx.x;
  const int p0 = chunk * kChunkP;
  const int p1 = min(p0 + kChunkP, kP);

  if (chunk == 0 && b == 0) {
    if (tid < kB) num_pos[tid] = 0;
    else if (tid < kB + 3) acc[tid - kB] = 0.0f;
    else if (tid == kB + 3) *counter = 0;
  }

  __shared__ float tx0[kT], ty0[kT], tx1[kT], ty1[kT], tarea[kT];
  __shared__ float swv[kT][4];
  __shared__ int swi[kT][4];

  if (tid < kT) {
    const float* tg = targets + (b * kT + tid) * 5;
    float x0 = tg[0], y0 = tg[1], x1 = tg[2], y1 = tg[3];
    tx0[tid] = x0; ty0[tid] = y0; tx1[tid] = x1; ty1[tid] = y1;
    tarea[tid] = (x1 - x0) * (y1 - y0);
  }
  __syncthreads();

  float bestv[kT];
  int besti[kT];
#pragma unroll
  for (int t = 0; t < kT; ++t) { bestv[t] = -1.0f; besti[t] = 0; }

  for (int p = p0 + tid; p < p1; p += 256) {
    float4 pr = reinterpret_cast<const float4*>(priors)[p];
    float px0 = pr.x - pr.z * 0.5f, py0 = pr.y - pr.w * 0.5f;
    float px1 = pr.x + pr.z * 0.5f, py1 = pr.y + pr.w * 0.5f;
    float parea = (px1 - px0) * (py1 - py0);
    float mv = -1.0f;
    int mt = 0;
#pragma unroll
    for (int t = 0; t < kT; ++t) {
      float lx = fmaxf(tx0[t], px0), ly = fmaxf(ty0[t], py0);
      float rx = fminf(tx1[t], px1), ry = fminf(ty1[t], py1);
      float w = fmaxf(rx - lx, 0.0f), h = fmaxf(ry - ly, 0.0f);
      float inter = w * h;
      float iou = inter / (tarea[t] + parea - inter);
      if (iou > bestv[t]) { bestv[t] = iou; besti[t] = p; }  // first idx wins
      if (iou > mv) { mv = iou; mt = t; }                    // first t wins
    }
    mcode[b * kP + p] = (unsigned char)(mt | (mv < kThresh ? 0x80 : 0));
  }

  // per-truth best prior within this chunk: shfl butterfly + tiny LDS
#pragma unroll
  for (int t = 0; t < kT; ++t) {
    float v = bestv[t];
    int i = besti[t];
    for (int off = 32; off > 0; off >>= 1) {
      float v2 = __shfl_xor(v, off, 64);
      int i2 = __shfl_xor(i, off, 64);
      if (v2 > v || (v2 == v && i2 < i)) { v = v2; i = i2; }
    }
    if ((tid & 63) == 0) { swv[t][tid >> 6] = v; swi[t][tid >> 6] = i; }
  }
  __syncthreads();
  if (tid < kT) {
    float v = swv[tid][0];
    int i = swi[tid][0];
#pragma unroll
    for (int w = 1; w < 4; ++w) {
      float v2 = swv[tid][w];
      int i2 = swi[tid][w];
      if (v2 > v || (v2 == v && i2 < i)) { v = v2; i = i2; }
    }
    // every thread processed >= 1 prior (chunk sizes 1555..1563 >= 256),
    // so v >= 0 and float bits are unsigned-monotone.
    unsigned long long pk = ((unsigned long long)__float_as_uint(v) << 32) |
                            (unsigned long long)(0xFFFFFFFFu - (unsigned)i);
    best_pc[((size_t)b * kT + tid) * kChunks + chunk] = pk;
  }
}

// ---------------------------------------------------------------------------
// Kernel B: fused conf-assignment + encode/smooth-L1 + cross-entropy.
// Grid = B*P/64 blocks x 256. Per block: stage 64x81 conf tile, reduce the
// 16 chunk-slots -> s_bp for the (up to 2) b's this block straddles, then
// per row (sub==0 lane): forcing (ascending j, last wins) -> conf -> ce;
// positives additionally do encode + smooth-L1. Replaces old match2 + ce.
// ---------------------------------------------------------------------------
__global__ __launch_bounds__(256) void ce_fused_kernel(
    const float* __restrict__ conf_data,      // [B*P, 81]
    const unsigned char* __restrict__ mcode,  // [B*P]
    const float* __restrict__ loc_data,       // [B*P, 4]
    const float* __restrict__ priors,         // [P, 4]
    const float* __restrict__ targets,        // [B,T,5]
    const unsigned long long* __restrict__ best_pc,  // [B,T,kChunks]
    float* __restrict__ loss_c,               // [B*P] out (0 at positives)
    int* __restrict__ num_pos,                // [B] atomicAdd
    float* __restrict__ acc) {                // [loss_l, pos_ce]
  __shared__ float tile[kRowsPerBlk * kC];    // 20736 B
  __shared__ unsigned char smc[kRowsPerBlk];
  __shared__ int s_bp[2][kT];
  __shared__ float sx0[2][kT], sy0[2][kT], sx1[2][kT], sy1[2][kT], slab[2][kT];
  __shared__ float swf_l[4], swf_p[4];
  __shared__ int swi0[4], swi1[4];

  const int tid = threadIdx.x;
  const long long base = (long long)blockIdx.x * kRowsPerBlk;  // first row
  const int b0 = (int)(base / kP);
  const long long split = (long long)(b0 + 1) * kP;  // first row of b0+1

  // stage conf tile (coalesced float4)
  const float4* src = reinterpret_cast<const float4*>(conf_data + base * kC);
  float4* dst = reinterpret_cast<float4*>(tile);
#pragma unroll
  for (int i = 0; i < 6; ++i) {
    int idx = tid + i * 256;
    if (idx < kRowsPerBlk * kC / 4) dst[idx] = src[idx];
  }
  // stage mcode (64 B, u32 loads; base*1 is 64-aligned)
  if (tid < kRowsPerBlk / 4)
    reinterpret_cast<unsigned int*>(smc)[tid] =
        reinterpret_cast<const unsigned int*>(mcode + base)[tid];
  // per-b best-prior reduction + target coords (32 threads, up to 2 b's)
  if (tid < 2 * kT) {
    const int which = tid >> 4, t = tid & 15;
    const int b = b0 + which;
    if (b < kB) {
      const unsigned long long* pc = best_pc + ((size_t)b * kT + t) * kChunks;
      unsigned long long m = pc[0];
#pragma unroll
      for (int c = 1; c < kChunks; ++c) { unsigned long long v = pc[c]; m = v > m ? v : m; }
      s_bp[which][t] = (int)(0xFFFFFFFFu - (unsigned)(m & 0xFFFFFFFFull));
      const float* tg = targets + ((size_t)b * kT + t) * 5;
      sx0[which][t] = tg[0]; sy0[which][t] = tg[1];
      sx1[which][t] = tg[2]; sy1[which][t] = tg[3];
      slab[which][t] = tg[4];
    }
  }
  __syncthreads();

  const int r = tid >> 2;   // row within block, quads wave-contiguous
  const int sub = tid & 3;
  const float* x = tile + r * kC;
  float m = -3.0e38f;
  for (int j = sub; j < kC; j += 4) m = fmaxf(m, x[j]);
  m = fmaxf(m, __shfl_xor(m, 1, 64));
  m = fmaxf(m, __shfl_xor(m, 2, 64));
  float s = 0.0f;
  for (int j = sub; j < kC; j += 4) s += __expf(x[j] - m);
  s += __shfl_xor(s, 1, 64);
  s += __shfl_xor(s, 2, 64);

  float lsum = 0.0f, posce = 0.0f;
  int pc0 = 0, pc1 = 0;
  if (sub == 0) {
    const long long row = base + r;
    const int which = (row >= split) ? 1 : 0;
    const int p = (int)(row - (long long)(b0 + which) * kP);
    int c = smc[r];
    int mt = c & 0x0F;
    bool neg = (c & 0x80) != 0;
    bool forced = false;
#pragma unroll
    for (int j = 0; j < kT; ++j) {  // ascending j: last wins (torch loop order)
      if (s_bp[which][j] == p) { mt = j; forced = true; }
    }
    int conf = (!forced && neg) ? 0 : ((int)slab[which][mt] + 1);
    float lse = __logf(s) + m;
    float ce = lse - x[conf];
    bool pos = conf > 0;
    loss_c[row] = pos ? 0.0f : ce;  // >= 0 always (lse >= x[conf])
    posce = pos ? ce : 0.0f;
    if (pos) {
      float4 pr = reinterpret_cast<const float4*>(priors)[p];
      float mx0 = sx0[which][mt], my0 = sy0[which][mt];
      float mx1 = sx1[which][mt], my1 = sy1[which][mt];
      float gcx = ((mx0 + mx1) * 0.5f - pr.x) / (0.1f * pr.z);
      float gcy = ((my0 + my1) * 0.5f - pr.y) / (0.1f * pr.w);
      float gw = logf((mx1 - mx0) / pr.z) / 0.2f;
      float gh = logf((my1 - my0) / pr.w) / 0.2f;
      float4 ld = reinterpret_cast<const float4*>(loc_data)[row];
      lsum = smooth_l1(ld.x - gcx) + smooth_l1(ld.y - gcy) +
             smooth_l1(ld.z - gw) + smooth_l1(ld.w - gh);
      if (which) pc1 = 1; else pc0 = 1;
    }
  }
  // block reduce: posce, lsum (float), pc0, pc1 (int)
  for (int off = 32; off > 0; off >>= 1) {
    posce += __shfl_down(posce, off, 64);
    lsum += __shfl_down(lsum, off, 64);
    pc0 += __shfl_down(pc0, off, 64);
    pc1 += __shfl_down(pc1, off, 64);
  }
  if ((tid & 63) == 0) {
    swf_p[tid >> 6] = posce; swf_l[tid >> 6] = lsum;
    swi0[tid >> 6] = pc0;    swi1[tid >> 6] = pc1;
  }
  __syncthreads();
  if (tid == 0) {
    float tp = swf_p[0] + swf_p[1] + swf_p[2] + swf_p[3];
    float tl = swf_l[0] + swf_l[1] + swf_l[2] + swf_l[3];
    int t0 = swi0[0] + swi0[1] + swi0[2] + swi0[3];
    int t1 = swi1[0] + swi1[1] + swi1[2] + swi1[3];
    if (tl != 0.0f) atomicAdd(acc + 0, tl);     // positives sparse: most
    if (tp != 0.0f) atomicAdd(acc + 1, tp);     // blocks skip all atomics
    if (t0) atomicAdd(&num_pos[b0], t0);
    if (t1) atomicAdd(&num_pos[b0 + 1], t1);
  }
}

// ---------------------------------------------------------------------------
// Kernel C: per-batch exact top-k sum of loss_c (proven 256-thread version)
// with fused last-block finalize (proven in round 2).
// ---------------------------------------------------------------------------
__global__ __launch_bounds__(256) void select_kernel(
    const float* __restrict__ loss_c,  // [B,P]
    const int* __restrict__ num_pos,   // [B]
    float* __restrict__ acc,           // [loss_l, pos_ce, neg_ce]
    int* __restrict__ counter,         // [1], pre-zeroed
    float* __restrict__ out) {         // [2] final outputs
  const int b = blockIdx.x;
  const int tid = threadIdx.x;
  const int k = min(3 * num_pos[b], kP - 1);
  __shared__ int swi[4];
  __shared__ float swf[4];

  if (k > 0) {  // uniform branch per block
    constexpr int kV4 = kP / 4;                  // 6250
    constexpr int kPer = (kV4 + 255) / 256;      // 25
    const float4* v4 = reinterpret_cast<const float4*>(loss_c + (long long)b * kP);
    float4 lv[kPer];
#pragma unroll
    for (int j = 0; j < kPer; ++j) {
      int i = tid + j * 256;
      lv[j] = (i < kV4) ? v4[i] : float4{0.0f, 0.0f, 0.0f, 0.0f};
      // zero padding is safe: cand > 0 in every count, and 0 is never > ans
    }

    unsigned int ans = 0;
    for (int bit = 30; bit >= 0; --bit) {  // bit 31 never set (nonneg floats)
      const unsigned int cand = ans | (1u << bit);
      int cnt = 0;
#pragma unroll
      for (int j = 0; j < kPer; ++j) {
        cnt += (__float_as_uint(lv[j].x) >= cand) + (__float_as_uint(lv[j].y) >= cand) +
               (__float_as_uint(lv[j].z) >= cand) + (__float_as_uint(lv[j].w) >= cand);
      }
      for (int off = 32; off > 0; off >>= 1) cnt += __shfl_down(cnt, off, 64);
      if ((tid & 63) == 0) swi[tid >> 6] = cnt;
      __syncthreads();
      int tot = swi[0] + swi[1] + swi[2] + swi[3];  // uniform across block
      if (tot >= k) ans = cand;
      __syncthreads();
    }
    // ans = k-th largest value's bits. Sum strict-greater, pad with ties.
    float sum = 0.0f;
    int cgt = 0;
#pragma unroll
    for (int j = 0; j < kPer; ++j) {
      if (__float_as_uint(lv[j].x) > ans) { sum += lv[j].x; ++cgt; }
      if (__float_as_uint(lv[j].y) > ans) { sum += lv[j].y; ++cgt; }
      if (__float_as_uint(lv[j].z) > ans) { sum += lv[j].z; ++cgt; }
      if (__float_as_uint(lv[j].w) > ans) { sum += lv[j].w; ++cgt; }
    }
    for (int off = 32; off > 0; off >>= 1) {
      sum += __shfl_down(sum, off, 64);
      cgt += __shfl_down(cgt, off, 64);
    }
    if ((tid & 63) == 0) { swf[tid >> 6] = sum; swi[tid >> 6] = cgt; }
    __syncthreads();
    if (tid == 0) {
      float st = swf[0] + swf[1] + swf[2] + swf[3];
      int ct = swi[0] + swi[1] + swi[2] + swi[3];
      atomicAdd(acc + 2, st + (float)(k - ct) * __uint_as_float(ans));
    }
  }

  // last-block finalize: order = (my neg-CE add) -> fence -> counter bump
  __threadfence();
  if (tid == 0) {
    int done = atomicAdd(counter, 1);
    if (done == kB - 1) {
      int np = 0;
      for (int i = 0; i < kB; ++i) np += num_pos[i];  // prior-kernel writes
      float N = fmaxf((float)np, 1.0f);
      float neg = atomicAdd(acc + 2, 0.0f);  // RMW read: sees all prior adds
      out[0] = acc[0] / N;                   // written by ce_fused (pre-launch)
      out[1] = (acc[1] + neg) / N;
    }
  }
}

}  // namespace

extern "C" void kernel_launch(void* const* d_in, const int* in_sizes, int n_in,
                              void* d_out, int out_size, void* d_ws, size_t ws_size,
                              hipStream_t stream) {
  const float* loc_data = (const float*)d_in[0];   // [B,P,4]
  const float* conf_data = (const float*)d_in[1];  // [B,P,81]
  const float* priors = (const float*)d_in[2];     // [P,4]
  const float* targets = (const float*)d_in[3];    // [B,T,5]
  float* out = (float*)d_out;                      // 2 floats

  // Workspace layout (~8.13 MB):
  //   [0, 6.4M)              loss_c float[B*P]
  //   [6.4M, 8.0M)           mcode u8[B*P]
  //   [8.0M, +131072)        best_pc u64[B*T*kChunks]  (written uncond.)
  //   [8131072, +256)        num_pos int[B]            (zeroed by match1)
  //   [8131328, +12)         acc: loss_l, pos_ce, neg_ce (zeroed by match1)
  //   [8131392, +4)          counter int[1]            (zeroed by match1)
  char* ws = (char*)d_ws;
  float* loss_c = (float*)ws;
  unsigned char* mcode = (unsigned char*)(ws + 6400000);
  unsigned long long* best_pc = (unsigned long long*)(ws + 8000000);
  int* num_pos = (int*)(ws + 8131072);
  float* acc = (float*)(ws + 8131328);
  int* counter = (int*)(ws + 8131392);

  hipLaunchKernelGGL(match1_kernel, dim3(kChunks, kB), dim3(256), 0, stream,
                     priors, targets, mcode, best_pc, num_pos, acc, counter);
  hipLaunchKernelGGL(ce_fused_kernel, dim3(kB * kP / kRowsPerBlk), dim3(256), 0,
                     stream, conf_data, mcode, loc_data, priors, targets,
                     best_pc, loss_c, num_pos, acc);
  hipLaunchKernelGGL(select_kernel, dim3(kB), dim3(256), 0, stream,
                     loss_c, num_pos, acc, counter, out);
}

// Round 4
// 827.809 us; speedup vs baseline: 1.1908x; 1.1908x over previous
//
#include <hip/hip_runtime.h>

namespace {

constexpr int kB = 64;
constexpr int kP = 25000;
constexpr int kT = 16;
constexpr int kC = 81;
constexpr int kRowsPerBlk = 64;            // ce kernel rows per block
constexpr int kChunks = 16;                // prior chunks for match kernels
constexpr int kChunkP = (kP + kChunks - 1) / kChunks;  // 1563
constexpr float kThresh = 0.5f;

__device__ __forceinline__ float smooth_l1(float d) {
  float ad = fabsf(d);
  return ad < 1.0f ? 0.5f * d * d : ad - 0.5f;
}

// ---------------------------------------------------------------------------
// Kernel A1: per-prior best truth -> mcode; per-(b,t,chunk) best prior written
// UNCONDITIONALLY to its own slot (no atomics -> no pre-zero -> no memset
// dispatch). Block (0,0) zeroes num_pos/acc/counter (consumed only by later
// kernels; the kernel boundary orders the writes). Ran verified in round 3.
// packed u64 = (iou_bits << 32) | (0xFFFFFFFF - p): max => max iou, ties
// prefer smaller p (first occurrence, matches jnp.argmax).
// ---------------------------------------------------------------------------
__global__ __launch_bounds__(256) void match1_kernel(
    const float* __restrict__ priors,     // [P,4] (cx,cy,w,h)
    const float* __restrict__ targets,    // [B,T,5]
    unsigned char* __restrict__ mcode,    // [B,P] out
    unsigned long long* __restrict__ best_pc,  // [B,T,kChunks] out
    int* __restrict__ num_pos,            // [B] zeroed here
    float* __restrict__ acc,              // [3] zeroed here
    int* __restrict__ counter) {          // [1] zeroed here
  const int chunk = blockIdx.x;
  const int b = blockIdx.y;
  const int tid = threadIdx.x;
  const int p0 = chunk * kChunkP;
  const int p1 = min(p0 + kChunkP, kP);

  if (chunk == 0 && b == 0) {
    if (tid < kB) num_pos[tid] = 0;
    else if (tid < kB + 3) acc[tid - kB] = 0.0f;
    else if (tid == kB + 3) *counter = 0;
  }

  __shared__ float tx0[kT], ty0[kT], tx1[kT], ty1[kT], tarea[kT];
  __shared__ float swv[kT][4];
  __shared__ int swi[kT][4];

  if (tid < kT) {
    const float* tg = targets + (b * kT + tid) * 5;
    float x0 = tg[0], y0 = tg[1], x1 = tg[2], y1 = tg[3];
    tx0[tid] = x0; ty0[tid] = y0; tx1[tid] = x1; ty1[tid] = y1;
    tarea[tid] = (x1 - x0) * (y1 - y0);
  }
  __syncthreads();

  float bestv[kT];
  int besti[kT];
#pragma unroll
  for (int t = 0; t < kT; ++t) { bestv[t] = -1.0f; besti[t] = 0; }

  for (int p = p0 + tid; p < p1; p += 256) {
    float4 pr = reinterpret_cast<const float4*>(priors)[p];
    float px0 = pr.x - pr.z * 0.5f, py0 = pr.y - pr.w * 0.5f;
    float px1 = pr.x + pr.z * 0.5f, py1 = pr.y + pr.w * 0.5f;
    float parea = (px1 - px0) * (py1 - py0);
    float mv = -1.0f;
    int mt = 0;
#pragma unroll
    for (int t = 0; t < kT; ++t) {
      float lx = fmaxf(tx0[t], px0), ly = fmaxf(ty0[t], py0);
      float rx = fminf(tx1[t], px1), ry = fminf(ty1[t], py1);
      float w = fmaxf(rx - lx, 0.0f), h = fmaxf(ry - ly, 0.0f);
      float inter = w * h;
      float iou = inter / (tarea[t] + parea - inter);
      if (iou > bestv[t]) { bestv[t] = iou; besti[t] = p; }  // first idx wins
      if (iou > mv) { mv = iou; mt = t; }                    // first t wins
    }
    mcode[b * kP + p] = (unsigned char)(mt | (mv < kThresh ? 0x80 : 0));
  }

  // per-truth best prior within this chunk: shfl butterfly + tiny LDS
#pragma unroll
  for (int t = 0; t < kT; ++t) {
    float v = bestv[t];
    int i = besti[t];
    for (int off = 32; off > 0; off >>= 1) {
      float v2 = __shfl_xor(v, off, 64);
      int i2 = __shfl_xor(i, off, 64);
      if (v2 > v || (v2 == v && i2 < i)) { v = v2; i = i2; }
    }
    if ((tid & 63) == 0) { swv[t][tid >> 6] = v; swi[t][tid >> 6] = i; }
  }
  __syncthreads();
  if (tid < kT) {
    float v = swv[tid][0];
    int i = swi[tid][0];
#pragma unroll
    for (int w = 1; w < 4; ++w) {
      float v2 = swv[tid][w];
      int i2 = swi[tid][w];
      if (v2 > v || (v2 == v && i2 < i)) { v = v2; i = i2; }
    }
    // every thread processed >= 1 prior (chunk sizes >= 256), so v >= 0 and
    // float bits are unsigned-monotone.
    unsigned long long pk = ((unsigned long long)__float_as_uint(v) << 32) |
                            (unsigned long long)(0xFFFFFFFFu - (unsigned)i);
    best_pc[((size_t)b * kT + tid) * kChunks + chunk] = pk;
  }
}

// ---------------------------------------------------------------------------
// Kernel A2: forcing + conf assignment + encode + smooth-L1 (round-2 proven
// semantics; only change: reduce the 16 best_pc chunk slots instead of one
// atomicMax'd word — 16 extra u64 loads in 16 threads, trivial).
// Grid (kChunks, kB) x 256. code[] read as mcode, overwritten as conf_t.
// ---------------------------------------------------------------------------
__global__ __launch_bounds__(256) void match2_kernel(
    const float* __restrict__ loc_data,   // [B,P,4]
    const float* __restrict__ priors,     // [P,4]
    const float* __restrict__ targets,    // [B,T,5]
    const unsigned long long* __restrict__ best_pc,  // [B,T,kChunks]
    unsigned char* __restrict__ code,     // [B,P] in: mcode, out: conf_t
    int* __restrict__ num_pos,            // [B], zeroed by match1, atomicAdd
    float* __restrict__ loss_l_acc) {     // [1], zeroed by match1
  const int chunk = blockIdx.x;
  const int b = blockIdx.y;
  const int tid = threadIdx.x;
  const int p0 = chunk * kChunkP;
  const int p1 = min(p0 + kChunkP, kP);

  __shared__ int s_bp[kT];
  __shared__ float sx0[kT], sy0[kT], sx1[kT], sy1[kT], slab[kT];
  __shared__ float swf[4];
  __shared__ int swi[4];

  if (tid < kT) {
    const unsigned long long* pc = best_pc + ((size_t)b * kT + tid) * kChunks;
    unsigned long long m = pc[0];
#pragma unroll
    for (int c = 1; c < kChunks; ++c) {
      unsigned long long v = pc[c];
      m = v > m ? v : m;
    }
    s_bp[tid] = (int)(0xFFFFFFFFu - (unsigned)(m & 0xFFFFFFFFull));
    const float* tg = targets + (b * kT + tid) * 5;
    sx0[tid] = tg[0]; sy0[tid] = tg[1]; sx1[tid] = tg[2]; sy1[tid] = tg[3];
    slab[tid] = tg[4];
  }
  __syncthreads();

  float lsum = 0.0f;
  int pcount = 0;
  for (int p = p0 + tid; p < p1; p += 256) {
    int c = code[b * kP + p];
    int mt = c & 0x0F;
    bool neg = (c & 0x80) != 0;
    bool forced = false;
#pragma unroll
    for (int j = 0; j < kT; ++j) {  // ascending j: last wins (torch loop order)
      if (s_bp[j] == p) { mt = j; forced = true; }
    }
    int conf = (!forced && neg) ? 0 : ((int)slab[mt] + 1);
    code[b * kP + p] = (unsigned char)conf;
    if (conf > 0) {
      ++pcount;
      float4 pr = reinterpret_cast<const float4*>(priors)[p];
      float mx0 = sx0[mt], my0 = sy0[mt], mx1 = sx1[mt], my1 = sy1[mt];
      float gcx = ((mx0 + mx1) * 0.5f - pr.x) / (0.1f * pr.z);
      float gcy = ((my0 + my1) * 0.5f - pr.y) / (0.1f * pr.w);
      float gw = logf((mx1 - mx0) / pr.z) / 0.2f;
      float gh = logf((my1 - my0) / pr.w) / 0.2f;
      float4 ld = reinterpret_cast<const float4*>(loc_data)[b * kP + p];
      lsum += smooth_l1(ld.x - gcx) + smooth_l1(ld.y - gcy) +
              smooth_l1(ld.z - gw) + smooth_l1(ld.w - gh);
    }
  }
  // wave reduce, then cross-wave via LDS
  for (int off = 32; off > 0; off >>= 1) {
    lsum += __shfl_down(lsum, off, 64);
    pcount += __shfl_down(pcount, off, 64);
  }
  if ((tid & 63) == 0) { swf[tid >> 6] = lsum; swi[tid >> 6] = pcount; }
  __syncthreads();
  if (tid == 0) {
    float lt = swf[0] + swf[1] + swf[2] + swf[3];
    int pt = swi[0] + swi[1] + swi[2] + swi[3];
    if (lt != 0.0f) atomicAdd(loss_l_acc, lt);
    if (pt != 0) atomicAdd(&num_pos[b], pt);
  }
}

// ---------------------------------------------------------------------------
// Kernel B: per-(b,p) cross-entropy via logsumexp. NEW single-pass core:
// each quad lane register-caches its 20 contiguous floats via independent
// ds_read_b32 (one lgkmcnt wait, no load-use chain), computes max over
// registers, 2 quad shuffles, exp-sum from registers (no 2nd LDS pass).
// Old core exposed ~120cy LDS latency ~42x per thread through a serial
// fmaxf/add chain -> 235us at 8.7% HBM. Bank pattern (17r+20s+i)%32 is
// <=2-way (free). Grid = B*P/64 blocks x 256.
// ---------------------------------------------------------------------------
__global__ __launch_bounds__(256) void ce_kernel(
    const float* __restrict__ conf_data,      // [B*P, 81]
    const unsigned char* __restrict__ conf_t, // [B*P]
    float* __restrict__ loss_c,               // [B*P] out (0 at positives)
    float* __restrict__ pos_ce_acc) {         // [1] accumulate
  __shared__ float tile[kRowsPerBlk * kC];    // 20736 B
  __shared__ float swsum[4];
  const int tid = threadIdx.x;
  const long long base = (long long)blockIdx.x * (kRowsPerBlk * kC);
  const float4* src = reinterpret_cast<const float4*>(conf_data + base);
  float4* dst = reinterpret_cast<float4*>(tile);
#pragma unroll
  for (int i = 0; i < 6; ++i) {
    int idx = tid + i * 256;
    if (idx < kRowsPerBlk * kC / 4) dst[idx] = src[idx];
  }
  __syncthreads();

  const int r = tid >> 2;   // row within block, quads are wave-contiguous
  const int sub = tid & 3;
  const float* x = tile + r * kC;

  // register-cache this lane's 20 floats: x[20*sub .. 20*sub+19]
  float xv[20];
  const float* xs = x + 20 * sub;
#pragma unroll
  for (int i = 0; i < 20; ++i) xv[i] = xs[i];
  float x80 = x[80];  // same addr within quad -> LDS broadcast (free)

  // max over registers, then 2-step quad butterfly
  float m = xv[0];
#pragma unroll
  for (int i = 1; i < 20; ++i) m = fmaxf(m, xv[i]);
  m = fmaxf(m, x80);
  m = fmaxf(m, __shfl_xor(m, 1, 64));
  m = fmaxf(m, __shfl_xor(m, 2, 64));

  // exp-sum from registers (x80 contributed by sub==0 only)
  float s = 0.0f;
#pragma unroll
  for (int i = 0; i < 20; ++i) s += __expf(xv[i] - m);
  if (sub == 0) s += __expf(x80 - m);
  s += __shfl_xor(s, 1, 64);
  s += __shfl_xor(s, 2, 64);

  float posce = 0.0f;
  if (sub == 0) {
    const long long row = (long long)blockIdx.x * kRowsPerBlk + r;
    float lse = __logf(s) + m;
    int ct = conf_t[row];
    float ce = lse - x[ct];
    bool pos = ct > 0;
    loss_c[row] = pos ? 0.0f : ce;  // >= 0 always (lse >= x[ct])
    posce = pos ? ce : 0.0f;
  }
  for (int off = 32; off > 0; off >>= 1) posce += __shfl_down(posce, off, 64);
  if ((tid & 63) == 0) swsum[tid >> 6] = posce;
  __syncthreads();
  if (tid == 0) {
    float t = swsum[0] + swsum[1] + swsum[2] + swsum[3];
    if (t != 0.0f) atomicAdd(pos_ce_acc, t);  // positives are sparse
  }
}

// ---------------------------------------------------------------------------
// Kernel C: per-batch exact top-k sum of loss_c (proven 256-thread version)
// with fused last-block finalize (proven rounds 2-3).
// ---------------------------------------------------------------------------
__global__ __launch_bounds__(256) void select_kernel(
    const float* __restrict__ loss_c,  // [B,P]
    const int* __restrict__ num_pos,   // [B]
    float* __restrict__ acc,           // [loss_l, pos_ce, neg_ce]
    int* __restrict__ counter,         // [1], zeroed by match1
    float* __restrict__ out) {         // [2] final outputs
  const int b = blockIdx.x;
  const int tid = threadIdx.x;
  const int k = min(3 * num_pos[b], kP - 1);
  __shared__ int swi[4];
  __shared__ float swf[4];

  if (k > 0) {  // uniform branch per block
    constexpr int kV4 = kP / 4;                  // 6250
    constexpr int kPer = (kV4 + 255) / 256;      // 25
    const float4* v4 = reinterpret_cast<const float4*>(loss_c + (long long)b * kP);
    float4 lv[kPer];
#pragma unroll
    for (int j = 0; j < kPer; ++j) {
      int i = tid + j * 256;
      lv[j] = (i < kV4) ? v4[i] : float4{0.0f, 0.0f, 0.0f, 0.0f};
      // zero padding is safe: cand > 0 in every count, and 0 is never > ans
    }

    unsigned int ans = 0;
    for (int bit = 30; bit >= 0; --bit) {  // bit 31 never set (nonneg floats)
      const unsigned int cand = ans | (1u << bit);
      int cnt = 0;
#pragma unroll
      for (int j = 0; j < kPer; ++j) {
        cnt += (__float_as_uint(lv[j].x) >= cand) + (__float_as_uint(lv[j].y) >= cand) +
               (__float_as_uint(lv[j].z) >= cand) + (__float_as_uint(lv[j].w) >= cand);
      }
      for (int off = 32; off > 0; off >>= 1) cnt += __shfl_down(cnt, off, 64);
      if ((tid & 63) == 0) swi[tid >> 6] = cnt;
      __syncthreads();
      int tot = swi[0] + swi[1] + swi[2] + swi[3];  // uniform across block
      if (tot >= k) ans = cand;
      __syncthreads();
    }
    // ans = k-th largest value's bits. Sum strict-greater, pad with ties.
    float sum = 0.0f;
    int cgt = 0;
#pragma unroll
    for (int j = 0; j < kPer; ++j) {
      if (__float_as_uint(lv[j].x) > ans) { sum += lv[j].x; ++cgt; }
      if (__float_as_uint(lv[j].y) > ans) { sum += lv[j].y; ++cgt; }
      if (__float_as_uint(lv[j].z) > ans) { sum += lv[j].z; ++cgt; }
      if (__float_as_uint(lv[j].w) > ans) { sum += lv[j].w; ++cgt; }
    }
    for (int off = 32; off > 0; off >>= 1) {
      sum += __shfl_down(sum, off, 64);
      cgt += __shfl_down(cgt, off, 64);
    }
    if ((tid & 63) == 0) { swf[tid >> 6] = sum; swi[tid >> 6] = cgt; }
    __syncthreads();
    if (tid == 0) {
      float st = swf[0] + swf[1] + swf[2] + swf[3];
      int ct = swi[0] + swi[1] + swi[2] + swi[3];
      atomicAdd(acc + 2, st + (float)(k - ct) * __uint_as_float(ans));
    }
  }

  // last-block finalize: order = (my neg-CE add) -> fence -> counter bump
  __threadfence();
  if (tid == 0) {
    int done = atomicAdd(counter, 1);
    if (done == kB - 1) {
      int np = 0;
      for (int i = 0; i < kB; ++i) np += num_pos[i];  // prior-kernel writes
      float N = fmaxf((float)np, 1.0f);
      float neg = atomicAdd(acc + 2, 0.0f);  // RMW read: sees all prior adds
      out[0] = acc[0] / N;                   // written by match2 (pre-launch)
      out[1] = (acc[1] + neg) / N;           // acc[1] written by ce (pre-launch)
    }
  }
}

}  // namespace

extern "C" void kernel_launch(void* const* d_in, const int* in_sizes, int n_in,
                              void* d_out, int out_size, void* d_ws, size_t ws_size,
                              hipStream_t stream) {
  const float* loc_data = (const float*)d_in[0];   // [B,P,4]
  const float* conf_data = (const float*)d_in[1];  // [B,P,81]
  const float* priors = (const float*)d_in[2];     // [P,4]
  const float* targets = (const float*)d_in[3];    // [B,T,5]
  float* out = (float*)d_out;                      // 2 floats

  // Workspace layout (~8.13 MB):
  //   [0, 6.4M)              loss_c float[B*P]
  //   [6.4M, 8.0M)           code u8[B*P] (mcode from match1, conf_t after match2)
  //   [8.0M, +131072)        best_pc u64[B*T*kChunks]  (written uncond.)
  //   [8131072, +256)        num_pos int[B]            (zeroed by match1)
  //   [8131328, +12)         acc: loss_l, pos_ce, neg_ce (zeroed by match1)
  //   [8131392, +4)          counter int[1]            (zeroed by match1)
  char* ws = (char*)d_ws;
  float* loss_c = (float*)ws;
  unsigned char* code = (unsigned char*)(ws + 6400000);
  unsigned long long* best_pc = (unsigned long long*)(ws + 8000000);
  int* num_pos = (int*)(ws + 8131072);
  float* acc = (float*)(ws + 8131328);
  int* counter = (int*)(ws + 8131392);

  hipLaunchKernelGGL(match1_kernel, dim3(kChunks, kB), dim3(256), 0, stream,
                     priors, targets, code, best_pc, num_pos, acc, counter);
  hipLaunchKernelGGL(match2_kernel, dim3(kChunks, kB), dim3(256), 0, stream,
                     loc_data, priors, targets, best_pc, code, num_pos, acc + 0);
  hipLaunchKernelGGL(ce_kernel, dim3(kB * kP / kRowsPerBlk), dim3(256), 0, stream,
                     conf_data, code, loss_c, acc + 1);
  hipLaunchKernelGGL(select_kernel, dim3(kB), dim3(256), 0, stream,
                     loss_c, num_pos, acc, counter, out);
}

// Round 5
// 823.256 us; speedup vs baseline: 1.1974x; 1.0055x over previous
//
#include <hip/hip_runtime.h>

namespace {

constexpr int kB = 64;
constexpr int kP = 25000;
constexpr int kT = 16;
constexpr int kC = 81;
constexpr int kRowsPerBlk = 64;            // ce kernel rows per block
constexpr int kChunks = 16;                // prior chunks for match kernels
constexpr int kChunkP = (kP + kChunks - 1) / kChunks;  // 1563
constexpr float kThresh = 0.5f;

__device__ __forceinline__ float smooth_l1(float d) {
  float ad = fabsf(d);
  return ad < 1.0f ? 0.5f * d * d : ad - 0.5f;
}

// ---------------------------------------------------------------------------
// Kernel A1: per-prior best truth -> mcode; per-(b,t,chunk) best prior written
// UNCONDITIONALLY to its own slot (no atomics -> no pre-zero -> no memset
// dispatch). Block (0,0) zeroes num_pos/acc/counter (consumed only by later
// kernels; the kernel boundary orders the writes). Proven rounds 3-4.
// packed u64 = (iou_bits << 32) | (0xFFFFFFFF - p): max => max iou, ties
// prefer smaller p (first occurrence, matches jnp.argmax).
// ---------------------------------------------------------------------------
__global__ __launch_bounds__(256) void match1_kernel(
    const float* __restrict__ priors,     // [P,4] (cx,cy,w,h)
    const float* __restrict__ targets,    // [B,T,5]
    unsigned char* __restrict__ mcode,    // [B,P] out
    unsigned long long* __restrict__ best_pc,  // [B,T,kChunks] out
    int* __restrict__ num_pos,            // [B] zeroed here
    float* __restrict__ acc,              // [3] zeroed here
    int* __restrict__ counter) {          // [1] zeroed here
  const int chunk = blockIdx.x;
  const int b = blockIdx.y;
  const int tid = threadIdx.x;
  const int p0 = chunk * kChunkP;
  const int p1 = min(p0 + kChunkP, kP);

  if (chunk == 0 && b == 0) {
    if (tid < kB) num_pos[tid] = 0;
    else if (tid < kB + 3) acc[tid - kB] = 0.0f;
    else if (tid == kB + 3) *counter = 0;
  }

  __shared__ float tx0[kT], ty0[kT], tx1[kT], ty1[kT], tarea[kT];
  __shared__ float swv[kT][4];
  __shared__ int swi[kT][4];

  if (tid < kT) {
    const float* tg = targets + (b * kT + tid) * 5;
    float x0 = tg[0], y0 = tg[1], x1 = tg[2], y1 = tg[3];
    tx0[tid] = x0; ty0[tid] = y0; tx1[tid] = x1; ty1[tid] = y1;
    tarea[tid] = (x1 - x0) * (y1 - y0);
  }
  __syncthreads();

  float bestv[kT];
  int besti[kT];
#pragma unroll
  for (int t = 0; t < kT; ++t) { bestv[t] = -1.0f; besti[t] = 0; }

  for (int p = p0 + tid; p < p1; p += 256) {
    float4 pr = reinterpret_cast<const float4*>(priors)[p];
    float px0 = pr.x - pr.z * 0.5f, py0 = pr.y - pr.w * 0.5f;
    float px1 = pr.x + pr.z * 0.5f, py1 = pr.y + pr.w * 0.5f;
    float parea = (px1 - px0) * (py1 - py0);
    float mv = -1.0f;
    int mt = 0;
#pragma unroll
    for (int t = 0; t < kT; ++t) {
      float lx = fmaxf(tx0[t], px0), ly = fmaxf(ty0[t], py0);
      float rx = fminf(tx1[t], px1), ry = fminf(ty1[t], py1);
      float w = fmaxf(rx - lx, 0.0f), h = fmaxf(ry - ly, 0.0f);
      float inter = w * h;
      float iou = inter / (tarea[t] + parea - inter);
      if (iou > bestv[t]) { bestv[t] = iou; besti[t] = p; }  // first idx wins
      if (iou > mv) { mv = iou; mt = t; }                    // first t wins
    }
    mcode[b * kP + p] = (unsigned char)(mt | (mv < kThresh ? 0x80 : 0));
  }

  // per-truth best prior within this chunk: shfl butterfly + tiny LDS
#pragma unroll
  for (int t = 0; t < kT; ++t) {
    float v = bestv[t];
    int i = besti[t];
    for (int off = 32; off > 0; off >>= 1) {
      float v2 = __shfl_xor(v, off, 64);
      int i2 = __shfl_xor(i, off, 64);
      if (v2 > v || (v2 == v && i2 < i)) { v = v2; i = i2; }
    }
    if ((tid & 63) == 0) { swv[t][tid >> 6] = v; swi[t][tid >> 6] = i; }
  }
  __syncthreads();
  if (tid < kT) {
    float v = swv[tid][0];
    int i = swi[tid][0];
#pragma unroll
    for (int w = 1; w < 4; ++w) {
      float v2 = swv[tid][w];
      int i2 = swi[tid][w];
      if (v2 > v || (v2 == v && i2 < i)) { v = v2; i = i2; }
    }
    // every thread processed >= 1 prior (chunk sizes >= 256), so v >= 0 and
    // float bits are unsigned-monotone.
    unsigned long long pk = ((unsigned long long)__float_as_uint(v) << 32) |
                            (unsigned long long)(0xFFFFFFFFu - (unsigned)i);
    best_pc[((size_t)b * kT + tid) * kChunks + chunk] = pk;
  }
}

// ---------------------------------------------------------------------------
// Kernel A2: forcing + conf assignment + encode + smooth-L1 (proven rounds
// 2/4; reduces the 16 best_pc chunk slots in 16 threads).
// Grid (kChunks, kB) x 256. code[] read as mcode, overwritten as conf_t.
// ---------------------------------------------------------------------------
__global__ __launch_bounds__(256) void match2_kernel(
    const float* __restrict__ loc_data,   // [B,P,4]
    const float* __restrict__ priors,     // [P,4]
    const float* __restrict__ targets,    // [B,T,5]
    const unsigned long long* __restrict__ best_pc,  // [B,T,kChunks]
    unsigned char* __restrict__ code,     // [B,P] in: mcode, out: conf_t
    int* __restrict__ num_pos,            // [B], zeroed by match1, atomicAdd
    float* __restrict__ loss_l_acc) {     // [1], zeroed by match1
  const int chunk = blockIdx.x;
  const int b = blockIdx.y;
  const int tid = threadIdx.x;
  const int p0 = chunk * kChunkP;
  const int p1 = min(p0 + kChunkP, kP);

  __shared__ int s_bp[kT];
  __shared__ float sx0[kT], sy0[kT], sx1[kT], sy1[kT], slab[kT];
  __shared__ float swf[4];
  __shared__ int swi[4];

  if (tid < kT) {
    const unsigned long long* pc = best_pc + ((size_t)b * kT + tid) * kChunks;
    unsigned long long m = pc[0];
#pragma unroll
    for (int c = 1; c < kChunks; ++c) {
      unsigned long long v = pc[c];
      m = v > m ? v : m;
    }
    s_bp[tid] = (int)(0xFFFFFFFFu - (unsigned)(m & 0xFFFFFFFFull));
    const float* tg = targets + (b * kT + tid) * 5;
    sx0[tid] = tg[0]; sy0[tid] = tg[1]; sx1[tid] = tg[2]; sy1[tid] = tg[3];
    slab[tid] = tg[4];
  }
  __syncthreads();

  float lsum = 0.0f;
  int pcount = 0;
  for (int p = p0 + tid; p < p1; p += 256) {
    int c = code[b * kP + p];
    int mt = c & 0x0F;
    bool neg = (c & 0x80) != 0;
    bool forced = false;
#pragma unroll
    for (int j = 0; j < kT; ++j) {  // ascending j: last wins (torch loop order)
      if (s_bp[j] == p) { mt = j; forced = true; }
    }
    int conf = (!forced && neg) ? 0 : ((int)slab[mt] + 1);
    code[b * kP + p] = (unsigned char)conf;
    if (conf > 0) {
      ++pcount;
      float4 pr = reinterpret_cast<const float4*>(priors)[p];
      float mx0 = sx0[mt], my0 = sy0[mt], mx1 = sx1[mt], my1 = sy1[mt];
      float gcx = ((mx0 + mx1) * 0.5f - pr.x) / (0.1f * pr.z);
      float gcy = ((my0 + my1) * 0.5f - pr.y) / (0.1f * pr.w);
      float gw = logf((mx1 - mx0) / pr.z) / 0.2f;
      float gh = logf((my1 - my0) / pr.w) / 0.2f;
      float4 ld = reinterpret_cast<const float4*>(loc_data)[b * kP + p];
      lsum += smooth_l1(ld.x - gcx) + smooth_l1(ld.y - gcy) +
              smooth_l1(ld.z - gw) + smooth_l1(ld.w - gh);
    }
  }
  // wave reduce, then cross-wave via LDS
  for (int off = 32; off > 0; off >>= 1) {
    lsum += __shfl_down(lsum, off, 64);
    pcount += __shfl_down(pcount, off, 64);
  }
  if ((tid & 63) == 0) { swf[tid >> 6] = lsum; swi[tid >> 6] = pcount; }
  __syncthreads();
  if (tid == 0) {
    float lt = swf[0] + swf[1] + swf[2] + swf[3];
    int pt = swi[0] + swi[1] + swi[2] + swi[3];
    if (lt != 0.0f) atomicAdd(loss_l_acc, lt);
    if (pt != 0) atomicAdd(&num_pos[b], pt);
  }
}

// ---------------------------------------------------------------------------
// Kernel B: per-(b,p) cross-entropy via logsumexp — BARRIER-FREE, LDS-FREE.
// R4 showed the LDS-read phase was not the bottleneck (register-cache rewrite
// was a null); the shared suspect is the staging+__syncthreads structure
// (every wave stalls on the block's slowest load; 21.6KB LDS caps residency
// at 7 blocks/CU). New core: each 4-lane quad owns one row; lane sub loads
// its 20 (21 for sub==3) elements as independent scalar dword loads straight
// into registers (row stride 324B is 4-mod-16 -> scalar dwords are the
// aligned form; 21 independent loads/lane = ample MLP). No barrier before
// compute, zero LDS in the hot path -> occupancy at the wave cap, no
// inter-wave coupling. Traffic unchanged (every line consumed exactly once).
// Grid = B*P/64 blocks x 256.
// ---------------------------------------------------------------------------
__global__ __launch_bounds__(256) void ce_kernel(
    const float* __restrict__ conf_data,      // [B*P, 81]
    const unsigned char* __restrict__ conf_t, // [B*P]
    float* __restrict__ loss_c,               // [B*P] out (0 at positives)
    float* __restrict__ pos_ce_acc) {         // [1] accumulate
  __shared__ float swsum[4];
  const int tid = threadIdx.x;
  const int q = tid >> 2;    // row within block
  const int sub = tid & 3;
  const long long row = (long long)blockIdx.x * kRowsPerBlk + q;
  const float* xr = conf_data + row * kC;

  // register-load this lane's elements: xr[20*sub .. 20*sub+19], sub3 also 80
  float xv[21];
  const float* xs = xr + 20 * sub;
#pragma unroll
  for (int i = 0; i < 20; ++i) xv[i] = xs[i];
  xv[20] = (sub == 3) ? xr[80] : -3.0e38f;  // exp(-3e38 - m) flushes to 0

  // max over registers, then 2-step quad butterfly
  float m = xv[0];
#pragma unroll
  for (int i = 1; i < 21; ++i) m = fmaxf(m, xv[i]);
  m = fmaxf(m, __shfl_xor(m, 1, 64));
  m = fmaxf(m, __shfl_xor(m, 2, 64));

  // exp-sum from registers
  float s = 0.0f;
#pragma unroll
  for (int i = 0; i < 21; ++i) s += __expf(xv[i] - m);
  s += __shfl_xor(s, 1, 64);
  s += __shfl_xor(s, 2, 64);

  float posce = 0.0f;
  if (sub == 0) {
    float lse = __logf(s) + m;
    int ct = conf_t[row];
    float ce = lse - xr[ct];   // line is L1/L2-hot (just read by this quad)
    bool pos = ct > 0;
    loss_c[row] = pos ? 0.0f : ce;  // >= 0 always (lse >= xr[ct])
    posce = pos ? ce : 0.0f;
  }
  for (int off = 32; off > 0; off >>= 1) posce += __shfl_down(posce, off, 64);
  if ((tid & 63) == 0) swsum[tid >> 6] = posce;
  __syncthreads();
  if (tid == 0) {
    float t = swsum[0] + swsum[1] + swsum[2] + swsum[3];
    if (t != 0.0f) atomicAdd(pos_ce_acc, t);  // positives are sparse
  }
}

// ---------------------------------------------------------------------------
// Kernel C: per-batch exact top-k sum of loss_c (proven 256-thread version)
// with fused last-block finalize (proven rounds 2-4).
// ---------------------------------------------------------------------------
__global__ __launch_bounds__(256) void select_kernel(
    const float* __restrict__ loss_c,  // [B,P]
    const int* __restrict__ num_pos,   // [B]
    float* __restrict__ acc,           // [loss_l, pos_ce, neg_ce]
    int* __restrict__ counter,         // [1], zeroed by match1
    float* __restrict__ out) {         // [2] final outputs
  const int b = blockIdx.x;
  const int tid = threadIdx.x;
  const int k = min(3 * num_pos[b], kP - 1);
  __shared__ int swi[4];
  __shared__ float swf[4];

  if (k > 0) {  // uniform branch per block
    constexpr int kV4 = kP / 4;                  // 6250
    constexpr int kPer = (kV4 + 255) / 256;      // 25
    const float4* v4 = reinterpret_cast<const float4*>(loss_c + (long long)b * kP);
    float4 lv[kPer];
#pragma unroll
    for (int j = 0; j < kPer; ++j) {
      int i = tid + j * 256;
      lv[j] = (i < kV4) ? v4[i] : float4{0.0f, 0.0f, 0.0f, 0.0f};
      // zero padding is safe: cand > 0 in every count, and 0 is never > ans
    }

    unsigned int ans = 0;
    for (int bit = 30; bit >= 0; --bit) {  // bit 31 never set (nonneg floats)
      const unsigned int cand = ans | (1u << bit);
      int cnt = 0;
#pragma unroll
      for (int j = 0; j < kPer; ++j) {
        cnt += (__float_as_uint(lv[j].x) >= cand) + (__float_as_uint(lv[j].y) >= cand) +
               (__float_as_uint(lv[j].z) >= cand) + (__float_as_uint(lv[j].w) >= cand);
      }
      for (int off = 32; off > 0; off >>= 1) cnt += __shfl_down(cnt, off, 64);
      if ((tid & 63) == 0) swi[tid >> 6] = cnt;
      __syncthreads();
      int tot = swi[0] + swi[1] + swi[2] + swi[3];  // uniform across block
      if (tot >= k) ans = cand;
      __syncthreads();
    }
    // ans = k-th largest value's bits. Sum strict-greater, pad with ties.
    float sum = 0.0f;
    int cgt = 0;
#pragma unroll
    for (int j = 0; j < kPer; ++j) {
      if (__float_as_uint(lv[j].x) > ans) { sum += lv[j].x; ++cgt; }
      if (__float_as_uint(lv[j].y) > ans) { sum += lv[j].y; ++cgt; }
      if (__float_as_uint(lv[j].z) > ans) { sum += lv[j].z; ++cgt; }
      if (__float_as_uint(lv[j].w) > ans) { sum += lv[j].w; ++cgt; }
    }
    for (int off = 32; off > 0; off >>= 1) {
      sum += __shfl_down(sum, off, 64);
      cgt += __shfl_down(cgt, off, 64);
    }
    if ((tid & 63) == 0) { swf[tid >> 6] = sum; swi[tid >> 6] = cgt; }
    __syncthreads();
    if (tid == 0) {
      float st = swf[0] + swf[1] + swf[2] + swf[3];
      int ct = swi[0] + swi[1] + swi[2] + swi[3];
      atomicAdd(acc + 2, st + (float)(k - ct) * __uint_as_float(ans));
    }
  }

  // last-block finalize: order = (my neg-CE add) -> fence -> counter bump
  __threadfence();
  if (tid == 0) {
    int done = atomicAdd(counter, 1);
    if (done == kB - 1) {
      int np = 0;
      for (int i = 0; i < kB; ++i) np += num_pos[i];  // prior-kernel writes
      float N = fmaxf((float)np, 1.0f);
      float neg = atomicAdd(acc + 2, 0.0f);  // RMW read: sees all prior adds
      out[0] = acc[0] / N;                   // written by match2 (pre-launch)
      out[1] = (acc[1] + neg) / N;           // acc[1] written by ce (pre-launch)
    }
  }
}

}  // namespace

extern "C" void kernel_launch(void* const* d_in, const int* in_sizes, int n_in,
                              void* d_out, int out_size, void* d_ws, size_t ws_size,
                              hipStream_t stream) {
  const float* loc_data = (const float*)d_in[0];   // [B,P,4]
  const float* conf_data = (const float*)d_in[1];  // [B,P,81]
  const float* priors = (const float*)d_in[2];     // [P,4]
  const float* targets = (const float*)d_in[3];    // [B,T,5]
  float* out = (float*)d_out;                      // 2 floats

  // Workspace layout (~8.13 MB):
  //   [0, 6.4M)              loss_c float[B*P]
  //   [6.4M, 8.0M)           code u8[B*P] (mcode from match1, conf_t after match2)
  //   [8.0M, +131072)        best_pc u64[B*T*kChunks]  (written uncond.)
  //   [8131072, +256)        num_pos int[B]            (zeroed by match1)
  //   [8131328, +12)         acc: loss_l, pos_ce, neg_ce (zeroed by match1)
  //   [8131392, +4)          counter int[1]            (zeroed by match1)
  char* ws = (char*)d_ws;
  float* loss_c = (float*)ws;
  unsigned char* code = (unsigned char*)(ws + 6400000);
  unsigned long long* best_pc = (unsigned long long*)(ws + 8000000);
  int* num_pos = (int*)(ws + 8131072);
  float* acc = (float*)(ws + 8131328);
  int* counter = (int*)(ws + 8131392);

  hipLaunchKernelGGL(match1_kernel, dim3(kChunks, kB), dim3(256), 0, stream,
                     priors, targets, code, best_pc, num_pos, acc, counter);
  hipLaunchKernelGGL(match2_kernel, dim3(kChunks, kB), dim3(256), 0, stream,
                     loc_data, priors, targets, best_pc, code, num_pos, acc + 0);
  hipLaunchKernelGGL(ce_kernel, dim3(kB * kP / kRowsPerBlk), dim3(256), 0, stream,
                     conf_data, code, loss_c, acc + 1);
  hipLaunchKernelGGL(select_kernel, dim3(kB), dim3(256), 0, stream,
                     loss_c, num_pos, acc, counter, out);
}